// Round 2
// baseline (125.025 us; speedup 1.0000x reference)
//
#include <hip/hip_runtime.h>

// Problem constants (from reference): B=4, N=256, E=512, fp32 everywhere.
#define B_ 4
#define N_ 256
#define E_ 512
#define TS 16

// ---------------------------------------------------------------------------
// Kernel 1: G[b,i,j] = dot(X[b,i,:], X[b,j,:])   (E-length dot, 256x256 out)
// grid: (N/TS, N/TS, B), block (TS,TS)
// ---------------------------------------------------------------------------
__global__ void gram_kernel(const float* __restrict__ X, float* __restrict__ G) {
    const int b  = blockIdx.z;
    const int tx = threadIdx.x, ty = threadIdx.y;
    const int i  = blockIdx.y * TS + ty;   // output row
    const int j  = blockIdx.x * TS + tx;   // output col
    __shared__ float As[TS][TS + 1];
    __shared__ float Bs[TS][TS + 1];
    const float* Xb = X + (size_t)b * N_ * E_;
    float acc = 0.f;
    for (int k0 = 0; k0 < E_; k0 += TS) {
        As[ty][tx] = Xb[(blockIdx.y * TS + ty) * E_ + k0 + tx];
        Bs[ty][tx] = Xb[(blockIdx.x * TS + ty) * E_ + k0 + tx];
        __syncthreads();
#pragma unroll
        for (int kk = 0; kk < TS; ++kk)
            acc += As[ty][kk] * Bs[tx][kk];
        __syncthreads();
    }
    G[((size_t)b * N_ + i) * N_ + j] = acc;
}

// ---------------------------------------------------------------------------
// Kernel 2: S[b,i,p] = sum_{n<=i} G[b,i,n] * Kw[n,p]
// grid: (N/TS (p), N/TS (i), B), block (TS,TS)
// ---------------------------------------------------------------------------
__global__ void s_kernel(const float* __restrict__ G, const float* __restrict__ Kw,
                         float* __restrict__ S) {
    const int b  = blockIdx.z;
    const int tx = threadIdx.x, ty = threadIdx.y;
    const int i  = blockIdx.y * TS + ty;
    const int p  = blockIdx.x * TS + tx;
    __shared__ float As[TS][TS + 1];
    __shared__ float Bs[TS][TS + 1];
    const float* Gb = G + (size_t)b * N_ * N_;
    float acc = 0.f;
    const int kmax = (blockIdx.y + 1) * TS;   // rows n > i contribute 0
    for (int k0 = 0; k0 < kmax; k0 += TS) {
        const int n = k0 + tx;
        As[ty][tx] = (n <= i) ? Gb[i * N_ + n] : 0.f;
        Bs[ty][tx] = Kw[(k0 + ty) * N_ + p];
        __syncthreads();
#pragma unroll
        for (int kk = 0; kk < TS; ++kk)
            acc += As[ty][kk] * Bs[kk][tx];
        __syncthreads();
    }
    S[((size_t)b * N_ + i) * N_ + p] = acc;
}

// ---------------------------------------------------------------------------
// Kernel 3: T[b,i,n] = sum_{p<=i} S[b,i,p] * Qw[n,p]   (B = Qw^T)
// grid: (N/TS (n), N/TS (i), B), block (TS,TS)
// ---------------------------------------------------------------------------
__global__ void t_kernel(const float* __restrict__ S, const float* __restrict__ Qw,
                         float* __restrict__ T) {
    const int b  = blockIdx.z;
    const int tx = threadIdx.x, ty = threadIdx.y;
    const int i  = blockIdx.y * TS + ty;
    const int n  = blockIdx.x * TS + tx;
    __shared__ float As[TS][TS + 1];
    __shared__ float Bs[TS][TS + 1];   // Bs[p_local][n_local]
    const float* Sb = S + (size_t)b * N_ * N_;
    float acc = 0.f;
    const int kmax = (blockIdx.y + 1) * TS;   // p > i contribute 0
    for (int k0 = 0; k0 < kmax; k0 += TS) {
        const int p = k0 + tx;
        As[ty][tx] = (p <= i) ? Sb[i * N_ + p] : 0.f;
        // coalesced read of Qw[n0+ty, k0+tx], transposed store into LDS
        Bs[tx][ty] = Qw[(blockIdx.x * TS + ty) * N_ + k0 + tx];
        __syncthreads();
#pragma unroll
        for (int kk = 0; kk < TS; ++kk)
            acc += As[ty][kk] * Bs[kk][tx];
        __syncthreads();
    }
    T[((size_t)b * N_ + i) * N_ + n] = acc;
}

// ---------------------------------------------------------------------------
// Kernel 4: avg[b,i] = sum_{n<=i} T[b,i,n] * G[b,i,n]
// grid: B*N blocks of 256 threads (one block per (b,i))
// ---------------------------------------------------------------------------
__global__ void avg_kernel(const float* __restrict__ G, const float* __restrict__ T,
                           float* __restrict__ avgv) {
    const int bi = blockIdx.x;           // b*N + i
    const int i  = bi & (N_ - 1);
    const int n  = threadIdx.x;
    float v = (n <= i) ? G[(size_t)bi * N_ + n] * T[(size_t)bi * N_ + n] : 0.f;
#pragma unroll
    for (int off = 32; off > 0; off >>= 1)
        v += __shfl_down(v, off, 64);
    __shared__ float red[4];
    const int lane = threadIdx.x & 63, wid = threadIdx.x >> 6;
    if (lane == 0) red[wid] = v;
    __syncthreads();
    if (threadIdx.x == 0)
        avgv[bi] = red[0] + red[1] + red[2] + red[3];
}

// ---------------------------------------------------------------------------
// Kernel 5: fit[b,i,m] = sum_{n<=i} T[b,i,n] * X[b,n,m];
//           out = X * (1 + fit - avg)
// grid: (E/TS (m), N/TS (i), B), block (TS,TS)
// ---------------------------------------------------------------------------
__global__ void out_kernel(const float* __restrict__ X, const float* __restrict__ T,
                           const float* __restrict__ avgv, float* __restrict__ out) {
    const int b  = blockIdx.z;
    const int tx = threadIdx.x, ty = threadIdx.y;
    const int i  = blockIdx.y * TS + ty;
    const int m  = blockIdx.x * TS + tx;
    __shared__ float As[TS][TS + 1];
    __shared__ float Bs[TS][TS + 1];
    const float* Xb = X + (size_t)b * N_ * E_;
    const float* Tb = T + (size_t)b * N_ * N_;
    float acc = 0.f;
    const int kmax = (blockIdx.y + 1) * TS;   // n > i contribute 0
    for (int k0 = 0; k0 < kmax; k0 += TS) {
        const int n = k0 + tx;
        As[ty][tx] = (n <= i) ? Tb[i * N_ + n] : 0.f;
        Bs[ty][tx] = Xb[(k0 + ty) * E_ + m];
        __syncthreads();
#pragma unroll
        for (int kk = 0; kk < TS; ++kk)
            acc += As[ty][kk] * Bs[kk][tx];
        __syncthreads();
    }
    const float xv = Xb[i * E_ + m];
    out[((size_t)b * N_ + i) * E_ + m] = xv * (1.f + acc - avgv[b * N_ + i]);
}

// ---------------------------------------------------------------------------
extern "C" void kernel_launch(void* const* d_in, const int* in_sizes, int n_in,
                              void* d_out, int out_size, void* d_ws, size_t ws_size,
                              hipStream_t stream) {
    const float* X  = (const float*)d_in[0];   // (B,N,E)
    const float* Qw = (const float*)d_in[1];   // (N,N)
    const float* Kw = (const float*)d_in[2];   // (N,N)
    float* out = (float*)d_out;                // (B,N,E)

    float* ws   = (float*)d_ws;
    float* G    = ws;                          // B*N*N
    float* S    = ws + (size_t)B_ * N_ * N_;   // B*N*N
    float* T    = S  + (size_t)B_ * N_ * N_;   // B*N*N
    float* avgv = T  + (size_t)B_ * N_ * N_;   // B*N

    dim3 blk(TS, TS);
    dim3 grid_nn(N_ / TS, N_ / TS, B_);
    dim3 grid_ne(E_ / TS, N_ / TS, B_);

    gram_kernel<<<grid_nn, blk, 0, stream>>>(X, G);
    s_kernel<<<grid_nn, blk, 0, stream>>>(G, Kw, S);
    t_kernel<<<grid_nn, blk, 0, stream>>>(S, Qw, T);
    avg_kernel<<<B_ * N_, 256, 0, stream>>>(G, T, avgv);
    out_kernel<<<grid_ne, blk, 0, stream>>>(X, T, avgv, out);
}

// Round 3
// 119.274 us; speedup vs baseline: 1.0482x; 1.0482x over previous
//
#include <hip/hip_runtime.h>

// Problem constants: B=4, N=256, E=512, fp32.
#define B_ 4
#define N_ 256
#define E_ 512
#define RPB 2   // rows per block (adjacent pair i0, i0+1)

// ---------------------------------------------------------------------------
// Kernel 0: QwT[p][n] = Qw[n][p]  (256x256 transpose, canonical LDS tile)
// grid (8,8), block (32,8)
// ---------------------------------------------------------------------------
__global__ void transpose_kernel(const float* __restrict__ Qw, float* __restrict__ QwT) {
    __shared__ float tile[32][33];
    const int bx = blockIdx.x * 32, by = blockIdx.y * 32;
    const int x = threadIdx.x, y = threadIdx.y;
    for (int j = y; j < 32; j += 8)
        tile[j][x] = Qw[(by + j) * N_ + bx + x];
    __syncthreads();
    for (int j = y; j < 32; j += 8)
        QwT[(bx + j) * N_ + by + x] = tile[x][j];
}

// ---------------------------------------------------------------------------
// Kernel 1: fully fused per-row-pair chain.
// For each (b, i): g[n]=dot(X[n],x_i) (n<=i); s[p]=sum_{n<=i} g[n]Kw[n,p];
// t[n]=sum_{p<=i} s[p]Qw[n,p]; avg=sum_{n<=i} t[n]g[n];
// out[i,m]=x_i[m]*(1 + sum_{n<=i} t[n]X[n,m] - avg).
// grid: 512 blocks (B * N/RPB), block: 256 threads (4 waves).
// ---------------------------------------------------------------------------
__global__ __launch_bounds__(256) void fused_kernel(
    const float* __restrict__ X, const float* __restrict__ Kw,
    const float* __restrict__ QwT, float* __restrict__ out) {

    const int blk = blockIdx.x;          // 0..511
    const int b   = blk >> 7;            // 128 row-pairs per batch
    const int j   = blk & 127;
    // complementary remap for batches 2,3 so co-resident blocks on a CU
    // carry balanced (2j, 254-2j) loop lengths
    const int jr  = (b >= 2) ? (127 - j) : j;
    const int i0  = jr * RPB;            // rows i0 (r=0) and i0+1 (r=1)
    const int imax = i0 + 1;

    const int tid  = threadIdx.x;
    const int lane = tid & 63, wid = tid >> 6;

    const float* __restrict__ Xb = X + (size_t)b * N_ * E_;

    __shared__ float xi [RPB][E_];   // the two query rows      (4 KB)
    __shared__ float g  [RPB][N_];   // gram rows               (2 KB)
    __shared__ float sl [RPB][N_];   // s rows                  (2 KB)
    __shared__ float tl [RPB][N_];   // t rows                  (2 KB)
    __shared__ float avgv[RPB];
    __shared__ float red[4][RPB];

    // ---- load x_{i0}, x_{i0+1} into LDS: 1024 floats = 256 float4
    {
        const int r = tid >> 7, c = tid & 127;     // c indexes float4
        ((float4*)xi[r])[c] = ((const float4*)(Xb + (size_t)(i0 + r) * E_))[c];
    }
    __syncthreads();

    // ---- Phase A: g[r][n] = dot(X[n], xi[r]) for n <= imax
    // lane l owns m = 8l..8l+7 of every row; wave w handles n = w, w+4, ...
    float xf0[8], xf1[8];
#pragma unroll
    for (int q = 0; q < 8; ++q) { xf0[q] = xi[0][lane * 8 + q]; xf1[q] = xi[1][lane * 8 + q]; }

    for (int n = wid; n <= imax; n += 4) {
        const float4 a0 = ((const float4*)(Xb + (size_t)n * E_))[lane * 2];
        const float4 a1 = ((const float4*)(Xb + (size_t)n * E_))[lane * 2 + 1];
        float p0 = a0.x*xf0[0] + a0.y*xf0[1] + a0.z*xf0[2] + a0.w*xf0[3]
                 + a1.x*xf0[4] + a1.y*xf0[5] + a1.z*xf0[6] + a1.w*xf0[7];
        float p1 = a0.x*xf1[0] + a0.y*xf1[1] + a0.z*xf1[2] + a0.w*xf1[3]
                 + a1.x*xf1[4] + a1.y*xf1[5] + a1.z*xf1[6] + a1.w*xf1[7];
#pragma unroll
        for (int off = 32; off > 0; off >>= 1) {
            p0 += __shfl_xor(p0, off, 64);
            p1 += __shfl_xor(p1, off, 64);
        }
        if (lane == 0) { g[0][n] = p0; g[1][n] = p1; }
    }
    __syncthreads();

    // ---- Phase B: s[r][p] = sum_{n<=i0+r} g[r][n] * Kw[n,p];  p = tid
    {
        float s0 = 0.f, s1 = 0.f;
#pragma unroll 4
        for (int n = 0; n <= i0; ++n) {
            const float kw = Kw[(size_t)n * N_ + tid];
            s0 += g[0][n] * kw;
            s1 += g[1][n] * kw;
        }
        s1 += g[1][imax] * Kw[(size_t)imax * N_ + tid];
        sl[0][tid] = s0;
        sl[1][tid] = s1;
    }
    __syncthreads();

    // ---- Phase C: t[r][n] = sum_{p<=i0+r} s[r][p] * QwT[p,n];  n = tid
    float t0 = 0.f, t1 = 0.f;
    {
#pragma unroll 4
        for (int p = 0; p <= i0; ++p) {
            const float qw = QwT[(size_t)p * N_ + tid];
            t0 += sl[0][p] * qw;
            t1 += sl[1][p] * qw;
        }
        t1 += sl[1][imax] * QwT[(size_t)imax * N_ + tid];
        tl[0][tid] = t0;
        tl[1][tid] = t1;
    }
    __syncthreads();

    // ---- avg[r] = sum_{n<=i0+r} t[r][n] * g[r][n]   (n = tid, block reduce)
    {
        float v0 = (tid <= i0)   ? t0 * g[0][tid] : 0.f;
        float v1 = (tid <= imax) ? t1 * g[1][tid] : 0.f;
#pragma unroll
        for (int off = 32; off > 0; off >>= 1) {
            v0 += __shfl_xor(v0, off, 64);
            v1 += __shfl_xor(v1, off, 64);
        }
        if (lane == 0) { red[wid][0] = v0; red[wid][1] = v1; }
        __syncthreads();
        if (tid == 0) {
            avgv[0] = red[0][0] + red[1][0] + red[2][0] + red[3][0];
            avgv[1] = red[0][1] + red[1][1] + red[2][1] + red[3][1];
        }
        __syncthreads();
    }

    // ---- Phase D: fit[r][m] = sum_{n<=i0+r} t[r][n] * X[n,m];  m = tid, tid+256
    {
        float f00 = 0.f, f01 = 0.f, f10 = 0.f, f11 = 0.f;
#pragma unroll 4
        for (int n = 0; n <= i0; ++n) {
            const float ta = tl[0][n];
            const float tb = tl[1][n];
            const float xa = Xb[(size_t)n * E_ + tid];
            const float xc = Xb[(size_t)n * E_ + tid + 256];
            f00 += ta * xa;  f01 += ta * xc;
            f10 += tb * xa;  f11 += tb * xc;
        }
        {
            const float tb = tl[1][imax];
            f10 += tb * Xb[(size_t)imax * E_ + tid];
            f11 += tb * Xb[(size_t)imax * E_ + tid + 256];
        }
        const float a0 = avgv[0], a1 = avgv[1];
        float* o0 = out + ((size_t)b * N_ + i0) * E_;
        float* o1 = o0 + E_;
        o0[tid]       = xi[0][tid]       * (1.f + f00 - a0);
        o0[tid + 256] = xi[0][tid + 256] * (1.f + f01 - a0);
        o1[tid]       = xi[1][tid]       * (1.f + f10 - a1);
        o1[tid + 256] = xi[1][tid + 256] * (1.f + f11 - a1);
    }
}

// ---------------------------------------------------------------------------
extern "C" void kernel_launch(void* const* d_in, const int* in_sizes, int n_in,
                              void* d_out, int out_size, void* d_ws, size_t ws_size,
                              hipStream_t stream) {
    const float* X  = (const float*)d_in[0];   // (B,N,E)
    const float* Qw = (const float*)d_in[1];   // (N,N)
    const float* Kw = (const float*)d_in[2];   // (N,N)
    float* out = (float*)d_out;                // (B,N,E)

    float* QwT = (float*)d_ws;                 // N*N floats = 256 KB

    transpose_kernel<<<dim3(8, 8), dim3(32, 8), 0, stream>>>(Qw, QwT);
    fused_kernel<<<B_ * (N_ / RPB), 256, 0, stream>>>(X, Kw, QwT, out);
}

// Round 4
// 103.944 us; speedup vs baseline: 1.2028x; 1.1475x over previous
//
#include <hip/hip_runtime.h>

// Problem constants: B=4, N=256, E=512, fp32.
#define B_ 4
#define N_ 256
#define E_ 512

// ---------------------------------------------------------------------------
// Kernel 0: QwT[p][n] = Qw[n][p]  (256x256 transpose)
// ---------------------------------------------------------------------------
__global__ void transpose_kernel(const float* __restrict__ Qw, float* __restrict__ QwT) {
    __shared__ float tile[32][33];
    const int bx = blockIdx.x * 32, by = blockIdx.y * 32;
    const int x = threadIdx.x, y = threadIdx.y;
    for (int j = y; j < 32; j += 8)
        tile[j][x] = Qw[(by + j) * N_ + bx + x];
    __syncthreads();
    for (int j = y; j < 32; j += 8)
        QwT[(bx + j) * N_ + by + x] = tile[x][j];
}

__device__ __forceinline__ void fma4(float4& a, float c, const float4& v) {
    a.x += c * v.x; a.y += c * v.y; a.z += c * v.z; a.w += c * v.w;
}

// ---------------------------------------------------------------------------
// Fused per-row-pair chain. Reductions split across the 4 waves (chain /4,
// 4x load parallelism), float4 global loads, zero-padded coefficient arrays
// (no per-iteration masks). One block = rows (i0, i0+1) of batch b.
// grid: 512, block: 256 (4 waves).
// ---------------------------------------------------------------------------
__global__ __launch_bounds__(256) void fused_kernel(
    const float* __restrict__ X, const float* __restrict__ Kw,
    const float* __restrict__ QwT, float* __restrict__ out) {

    const int blk = blockIdx.x;          // 0..511
    const int b   = blk >> 7;
    const int j   = blk & 127;
    const int jr  = (b >= 2) ? (127 - j) : j;   // balance work across XCD/CU
    const int i0  = jr * 2;
    const int imax = i0 + 1;

    const int tid  = threadIdx.x;
    const int lane = tid & 63, wid = tid >> 6;

    const float*  __restrict__ Xb  = X + (size_t)b * N_ * E_;
    const float4* __restrict__ Xb4 = (const float4*)Xb;           // row stride 128
    const float4* __restrict__ Kw4 = (const float4*)Kw;           // row stride 64
    const float4* __restrict__ Qt4 = (const float4*)QwT;          // row stride 64

    __shared__ float  xi[2][E_];       // 4 KB
    __shared__ float  g [2][N_];       // 2 KB  (zero-padded)
    __shared__ float  sl[2][N_];       // 2 KB  (zero-padded)
    __shared__ float  tl[2][N_];       // 2 KB  (zero-padded)
    __shared__ float4 sp[4][2][128];   // 16 KB partial-reduce buffer (union B/C/D)
    __shared__ float  avgv[2];
    __shared__ float  red[4][2];
    float* const spf = (float*)sp;     // spf[(w*2+r)*512 + idx]

    // ---- load x_i0, x_i0+1; zero-init g
    {
        const int r = tid >> 7, c = tid & 127;
        ((float4*)xi[r])[c] = Xb4[(size_t)(i0 + r) * 128 + c];
        g[0][tid] = 0.f;
        g[1][tid] = 0.f;
    }
    __syncthreads();

    // rounded reduction bound: multiple of 16, >= imax+1, <= 256
    const int Mc  = (imax + 16) & ~15;
    const int cnt = Mc >> 2;           // per-wave chunk (multiple of 4)
    const int nb  = wid * cnt;

    // ---- Phase A: g[r][n] = dot(X[n], xi[r]), n <= imax (wave-strided n)
    {
        float xf0[8], xf1[8];
#pragma unroll
        for (int q = 0; q < 8; ++q) {
            xf0[q] = xi[0][lane * 8 + q];
            xf1[q] = xi[1][lane * 8 + q];
        }
        for (int n = wid; n <= imax; n += 4) {
            const float4 a0 = Xb4[(size_t)n * 128 + lane * 2];
            const float4 a1 = Xb4[(size_t)n * 128 + lane * 2 + 1];
            float p0 = a0.x*xf0[0] + a0.y*xf0[1] + a0.z*xf0[2] + a0.w*xf0[3]
                     + a1.x*xf0[4] + a1.y*xf0[5] + a1.z*xf0[6] + a1.w*xf0[7];
            float p1 = a0.x*xf1[0] + a0.y*xf1[1] + a0.z*xf1[2] + a0.w*xf1[3]
                     + a1.x*xf1[4] + a1.y*xf1[5] + a1.z*xf1[6] + a1.w*xf1[7];
#pragma unroll
            for (int off = 32; off > 0; off >>= 1) {
                p0 += __shfl_xor(p0, off, 64);
                p1 += __shfl_xor(p1, off, 64);
            }
            if (lane == 0) {
                if (n <= i0) g[0][n] = p0;   // row 0 masked at i0
                g[1][n] = p1;
            }
        }
    }
    __syncthreads();

    // ---- Phase B: s[r][p] = sum_n g[r][n] * Kw[n][p]   (wave-chunked n)
    {
        float4 a0 = {0,0,0,0}, a1 = {0,0,0,0};
        for (int jj = 0; jj < cnt; jj += 4) {
            const int n0 = nb + jj;
            const float4 k0 = Kw4[(size_t)(n0+0)*64 + lane];
            const float4 k1 = Kw4[(size_t)(n0+1)*64 + lane];
            const float4 k2 = Kw4[(size_t)(n0+2)*64 + lane];
            const float4 k3 = Kw4[(size_t)(n0+3)*64 + lane];
            fma4(a0, g[0][n0+0], k0); fma4(a1, g[1][n0+0], k0);
            fma4(a0, g[0][n0+1], k1); fma4(a1, g[1][n0+1], k1);
            fma4(a0, g[0][n0+2], k2); fma4(a1, g[1][n0+2], k2);
            fma4(a0, g[0][n0+3], k3); fma4(a1, g[1][n0+3], k3);
        }
        sp[wid][0][lane] = a0;
        sp[wid][1][lane] = a1;
    }
    __syncthreads();
    {
        const float s0 = spf[0*512+tid] + spf[2*512+tid] + spf[4*512+tid] + spf[6*512+tid];
        const float s1 = spf[1*512+tid] + spf[3*512+tid] + spf[5*512+tid] + spf[7*512+tid];
        sl[0][tid] = (tid <= i0)   ? s0 : 0.f;   // zero-pad for C's p-mask
        sl[1][tid] = (tid <= imax) ? s1 : 0.f;
    }
    __syncthreads();

    // ---- Phase C: t[r][n] = sum_p sl[r][p] * QwT[p][n]   (wave-chunked p)
    {
        float4 a0 = {0,0,0,0}, a1 = {0,0,0,0};
        for (int jj = 0; jj < cnt; jj += 4) {
            const int p0 = nb + jj;
            const float4 q0 = Qt4[(size_t)(p0+0)*64 + lane];
            const float4 q1 = Qt4[(size_t)(p0+1)*64 + lane];
            const float4 q2 = Qt4[(size_t)(p0+2)*64 + lane];
            const float4 q3 = Qt4[(size_t)(p0+3)*64 + lane];
            fma4(a0, sl[0][p0+0], q0); fma4(a1, sl[1][p0+0], q0);
            fma4(a0, sl[0][p0+1], q1); fma4(a1, sl[1][p0+1], q1);
            fma4(a0, sl[0][p0+2], q2); fma4(a1, sl[1][p0+2], q2);
            fma4(a0, sl[0][p0+3], q3); fma4(a1, sl[1][p0+3], q3);
        }
        sp[wid][0][lane] = a0;
        sp[wid][1][lane] = a1;
    }
    __syncthreads();
    {
        const float t0 = spf[0*512+tid] + spf[2*512+tid] + spf[4*512+tid] + spf[6*512+tid];
        const float t1 = spf[1*512+tid] + spf[3*512+tid] + spf[5*512+tid] + spf[7*512+tid];
        tl[0][tid] = (tid <= i0)   ? t0 : 0.f;   // zero-pad for D's n-mask
        tl[1][tid] = (tid <= imax) ? t1 : 0.f;
    }
    __syncthreads();

    // ---- avg[r] = sum_n tl[r][n] * g[r][n]  (both zero-padded -> no mask)
    {
        float v0 = tl[0][tid] * g[0][tid];
        float v1 = tl[1][tid] * g[1][tid];
#pragma unroll
        for (int off = 32; off > 0; off >>= 1) {
            v0 += __shfl_xor(v0, off, 64);
            v1 += __shfl_xor(v1, off, 64);
        }
        if (lane == 0) { red[wid][0] = v0; red[wid][1] = v1; }
        __syncthreads();
        if (tid == 0) {
            avgv[0] = red[0][0] + red[1][0] + red[2][0] + red[3][0];
            avgv[1] = red[0][1] + red[1][1] + red[2][1] + red[3][1];
        }
    }
    __syncthreads();

    // ---- Phase D: fit[r][m] = sum_n tl[r][n] * X[n][m]   (wave-chunked n)
    {
        float4 f00 = {0,0,0,0}, f01 = {0,0,0,0};   // row 0, m-blocks 0/1
        float4 f10 = {0,0,0,0}, f11 = {0,0,0,0};   // row 1
        for (int jj = 0; jj < cnt; jj += 2) {
            const int n0 = nb + jj;
            const float4 xa0 = Xb4[(size_t)(n0  )*128 + lane];
            const float4 xb0 = Xb4[(size_t)(n0  )*128 + 64 + lane];
            const float4 xa1 = Xb4[(size_t)(n0+1)*128 + lane];
            const float4 xb1 = Xb4[(size_t)(n0+1)*128 + 64 + lane];
            const float ta0 = tl[0][n0], tb0 = tl[1][n0];
            const float ta1 = tl[0][n0+1], tb1 = tl[1][n0+1];
            fma4(f00, ta0, xa0); fma4(f00, ta1, xa1);
            fma4(f01, ta0, xb0); fma4(f01, ta1, xb1);
            fma4(f10, tb0, xa0); fma4(f10, tb1, xa1);
            fma4(f11, tb0, xb0); fma4(f11, tb1, xb1);
        }
        sp[wid][0][lane]      = f00;
        sp[wid][0][64 + lane] = f01;
        sp[wid][1][lane]      = f10;
        sp[wid][1][64 + lane] = f11;
    }
    __syncthreads();
    {
        const float a0 = avgv[0], a1 = avgv[1];
        float* const o0 = out + ((size_t)b * N_ + i0) * E_;
        float* const o1 = o0 + E_;
#pragma unroll
        for (int h = 0; h < 2; ++h) {
            const int m = tid + h * 256;
            const float fit0 = spf[0*512+m] + spf[2*512+m] + spf[4*512+m] + spf[6*512+m];
            const float fit1 = spf[1*512+m] + spf[3*512+m] + spf[5*512+m] + spf[7*512+m];
            o0[m] = xi[0][m] * (1.f + fit0 - a0);
            o1[m] = xi[1][m] * (1.f + fit1 - a1);
        }
    }
}

// ---------------------------------------------------------------------------
extern "C" void kernel_launch(void* const* d_in, const int* in_sizes, int n_in,
                              void* d_out, int out_size, void* d_ws, size_t ws_size,
                              hipStream_t stream) {
    const float* X  = (const float*)d_in[0];   // (B,N,E)
    const float* Qw = (const float*)d_in[1];   // (N,N)
    const float* Kw = (const float*)d_in[2];   // (N,N)
    float* out = (float*)d_out;                // (B,N,E)

    float* QwT = (float*)d_ws;                 // 256 KB

    transpose_kernel<<<dim3(8, 8), dim3(32, 8), 0, stream>>>(Qw, QwT);
    fused_kernel<<<B_ * (N_ / 2), 256, 0, stream>>>(X, Kw, QwT, out);
}

// Round 5
// 82.760 us; speedup vs baseline: 1.5107x; 1.2560x over previous
//
#include <hip/hip_runtime.h>

// Problem constants: B=4, N=256, E=512, fp32.
#define B_ 4
#define N_ 256
#define E_ 512

// ws layout (floats): QwT[256*256], Gpart[16][256*256]  (~4.25 MB total)

// ---------------------------------------------------------------------------
// prep_kernel: grid (4,4,17), block (16,16).
//  bz in 0..15 : split-K Gram partial.  b = bz>>2, kq = bz&3.
//     Gpart[kq*4+b][i][j] = sum_{k in kq*128..+127} X[b,i,k] X[b,j,k]
//     64x64 output tile per block, 4x4 register fragment per thread,
//     k-transposed LDS tiles so fragments are ds_read_b128.
//  bz == 16   : 16 blocks transpose Qw (64x64 region each) -> QwT.
// ---------------------------------------------------------------------------
__global__ __launch_bounds__(256) void prep_kernel(
    const float* __restrict__ X, const float* __restrict__ Qw,
    float* __restrict__ QwT, float* __restrict__ Gpart) {

    const int bx = blockIdx.x, by = blockIdx.y, bz = blockIdx.z;
    const int tx = threadIdx.x, ty = threadIdx.y;
    const int tid = ty * 16 + tx;

    if (bz == 16) {
        // ---- transpose region: QwT[p][n] = Qw[n][p], p in bx*64.., n in by*64..
        __shared__ float tt[64][68];
        const int r = tid >> 2, c0 = tid & 3;
#pragma unroll
        for (int cc = 0; cc < 4; ++cc) {
            const int c = (c0 + cc * 4) * 4;          // p-local
            const float4 v = *(const float4*)&Qw[(by * 64 + r) * N_ + bx * 64 + c];
            tt[c + 0][r] = v.x; tt[c + 1][r] = v.y;
            tt[c + 2][r] = v.z; tt[c + 3][r] = v.w;
        }
        __syncthreads();
#pragma unroll
        for (int cc = 0; cc < 4; ++cc) {
            const int c = (c0 + cc * 4) * 4;          // n-local
            const float4 v = *(const float4*)&tt[r][c];
            *(float4*)&QwT[(bx * 64 + r) * N_ + by * 64 + c] = v;
        }
        return;
    }

    // ---- Gram split-K partial
    const int b = bz >> 2, kq = bz & 3;
    const float* __restrict__ Xb = X + (size_t)b * N_ * E_;
    __shared__ float At[32][68];   // At[k][i-local]
    __shared__ float Bt[32][68];   // Bt[k][j-local]
    float acc[4][4] = {};
    const int r = tid >> 2, c0 = tid & 3;

    for (int k0 = kq * 128; k0 < kq * 128 + 128; k0 += 32) {
        {
            const float4 va = *(const float4*)&Xb[(size_t)(by * 64 + r) * E_ + k0 + c0 * 8];
            const float4 vb = *(const float4*)&Xb[(size_t)(by * 64 + r) * E_ + k0 + c0 * 8 + 4];
            At[c0*8+0][r] = va.x; At[c0*8+1][r] = va.y; At[c0*8+2][r] = va.z; At[c0*8+3][r] = va.w;
            At[c0*8+4][r] = vb.x; At[c0*8+5][r] = vb.y; At[c0*8+6][r] = vb.z; At[c0*8+7][r] = vb.w;
            const float4 wa = *(const float4*)&Xb[(size_t)(bx * 64 + r) * E_ + k0 + c0 * 8];
            const float4 wb = *(const float4*)&Xb[(size_t)(bx * 64 + r) * E_ + k0 + c0 * 8 + 4];
            Bt[c0*8+0][r] = wa.x; Bt[c0*8+1][r] = wa.y; Bt[c0*8+2][r] = wa.z; Bt[c0*8+3][r] = wa.w;
            Bt[c0*8+4][r] = wb.x; Bt[c0*8+5][r] = wb.y; Bt[c0*8+6][r] = wb.z; Bt[c0*8+7][r] = wb.w;
        }
        __syncthreads();
#pragma unroll
        for (int kk = 0; kk < 32; ++kk) {
            const float4 a  = *(const float4*)&At[kk][ty * 4];
            const float4 bb = *(const float4*)&Bt[kk][tx * 4];
            acc[0][0] += a.x*bb.x; acc[0][1] += a.x*bb.y; acc[0][2] += a.x*bb.z; acc[0][3] += a.x*bb.w;
            acc[1][0] += a.y*bb.x; acc[1][1] += a.y*bb.y; acc[1][2] += a.y*bb.z; acc[1][3] += a.y*bb.w;
            acc[2][0] += a.z*bb.x; acc[2][1] += a.z*bb.y; acc[2][2] += a.z*bb.z; acc[2][3] += a.z*bb.w;
            acc[3][0] += a.w*bb.x; acc[3][1] += a.w*bb.y; acc[3][2] += a.w*bb.z; acc[3][3] += a.w*bb.w;
        }
        __syncthreads();
    }
    float* gout = Gpart + ((size_t)(kq * 4 + b) * N_ + by * 64 + ty * 4) * N_ + bx * 64 + tx * 4;
#pragma unroll
    for (int qi = 0; qi < 4; ++qi)
        *(float4*)&gout[(size_t)qi * N_] =
            make_float4(acc[qi][0], acc[qi][1], acc[qi][2], acc[qi][3]);
}

__device__ __forceinline__ void fma4(float4& a, float c, const float4& v) {
    a.x += c * v.x; a.y += c * v.y; a.z += c * v.z; a.w += c * v.w;
}

// ---------------------------------------------------------------------------
// fusedBCD: per-row-pair s -> t -> avg -> fit -> out, G read from Gpart.
// grid 512, block 256 (4 waves).
// ---------------------------------------------------------------------------
__global__ __launch_bounds__(256) void fused_kernel(
    const float* __restrict__ X, const float* __restrict__ Kw,
    const float* __restrict__ QwT, const float* __restrict__ Gpart,
    float* __restrict__ out) {

    const int blk = blockIdx.x;
    const int b   = blk >> 7;
    const int j   = blk & 127;
    const int jr  = (b >= 2) ? (127 - j) : j;   // work-balance pairing per CU
    const int i0  = jr * 2;
    const int imax = i0 + 1;

    const int tid  = threadIdx.x;
    const int lane = tid & 63, wid = tid >> 6;

    const float*  __restrict__ Xb  = X + (size_t)b * N_ * E_;
    const float4* __restrict__ Xb4 = (const float4*)Xb;     // row stride 128
    const float4* __restrict__ Kw4 = (const float4*)Kw;     // row stride 64
    const float4* __restrict__ Qt4 = (const float4*)QwT;    // row stride 64

    __shared__ float  xi[2][E_];       // 4 KB
    __shared__ float  g [2][N_];       // zero-padded
    __shared__ float  sl[2][N_];       // zero-padded
    __shared__ float  tl[2][N_];       // zero-padded
    __shared__ float4 sp[4][2][128];   // 16 KB partial-reduce buffer
    __shared__ float  avgv[2];
    __shared__ float  red[4][2];
    float* const spf = (float*)sp;     // spf[(w*2+r)*512 + idx]

    // ---- load x rows; g from Gpart (sum 4 K-quarters), masked
    {
        const int r = tid >> 7, c = tid & 127;
        ((float4*)xi[r])[c] = Xb4[(size_t)(i0 + r) * 128 + c];
    }
    {
        float s0 = 0.f, s1 = 0.f;
#pragma unroll
        for (int q = 0; q < 4; ++q) {
            s0 += Gpart[((size_t)(q * 4 + b) * N_ + i0)     * N_ + tid];
            s1 += Gpart[((size_t)(q * 4 + b) * N_ + i0 + 1) * N_ + tid];
        }
        g[0][tid] = (tid <= i0)   ? s0 : 0.f;
        g[1][tid] = (tid <= imax) ? s1 : 0.f;
    }
    __syncthreads();

    // rounded reduction bound: multiple of 16
    const int Mc  = (imax + 16) & ~15;
    const int cnt = Mc >> 2;           // per-wave chunk (multiple of 4)
    const int nb  = wid * cnt;

    // ---- Phase B: s[r][p] = sum_n g[r][n] * Kw[n][p]   (wave-chunked n)
    {
        float4 a0 = {0,0,0,0}, a1 = {0,0,0,0};
        for (int jj = 0; jj < cnt; jj += 4) {
            const int n0 = nb + jj;
            const float4 k0 = Kw4[(size_t)(n0+0)*64 + lane];
            const float4 k1 = Kw4[(size_t)(n0+1)*64 + lane];
            const float4 k2 = Kw4[(size_t)(n0+2)*64 + lane];
            const float4 k3 = Kw4[(size_t)(n0+3)*64 + lane];
            fma4(a0, g[0][n0+0], k0); fma4(a1, g[1][n0+0], k0);
            fma4(a0, g[0][n0+1], k1); fma4(a1, g[1][n0+1], k1);
            fma4(a0, g[0][n0+2], k2); fma4(a1, g[1][n0+2], k2);
            fma4(a0, g[0][n0+3], k3); fma4(a1, g[1][n0+3], k3);
        }
        sp[wid][0][lane] = a0;
        sp[wid][1][lane] = a1;
    }
    __syncthreads();
    {
        const float s0 = spf[0*512+tid] + spf[2*512+tid] + spf[4*512+tid] + spf[6*512+tid];
        const float s1 = spf[1*512+tid] + spf[3*512+tid] + spf[5*512+tid] + spf[7*512+tid];
        sl[0][tid] = (tid <= i0)   ? s0 : 0.f;
        sl[1][tid] = (tid <= imax) ? s1 : 0.f;
    }
    __syncthreads();

    // ---- Phase C: t[r][n] = sum_p sl[r][p] * QwT[p][n]   (wave-chunked p)
    {
        float4 a0 = {0,0,0,0}, a1 = {0,0,0,0};
        for (int jj = 0; jj < cnt; jj += 4) {
            const int p0 = nb + jj;
            const float4 q0 = Qt4[(size_t)(p0+0)*64 + lane];
            const float4 q1 = Qt4[(size_t)(p0+1)*64 + lane];
            const float4 q2 = Qt4[(size_t)(p0+2)*64 + lane];
            const float4 q3 = Qt4[(size_t)(p0+3)*64 + lane];
            fma4(a0, sl[0][p0+0], q0); fma4(a1, sl[1][p0+0], q0);
            fma4(a0, sl[0][p0+1], q1); fma4(a1, sl[1][p0+1], q1);
            fma4(a0, sl[0][p0+2], q2); fma4(a1, sl[1][p0+2], q2);
            fma4(a0, sl[0][p0+3], q3); fma4(a1, sl[1][p0+3], q3);
        }
        sp[wid][0][lane] = a0;
        sp[wid][1][lane] = a1;
    }
    __syncthreads();
    {
        const float t0 = spf[0*512+tid] + spf[2*512+tid] + spf[4*512+tid] + spf[6*512+tid];
        const float t1 = spf[1*512+tid] + spf[3*512+tid] + spf[5*512+tid] + spf[7*512+tid];
        tl[0][tid] = (tid <= i0)   ? t0 : 0.f;
        tl[1][tid] = (tid <= imax) ? t1 : 0.f;
    }
    __syncthreads();

    // ---- avg[r] = sum_n tl[r][n] * g[r][n]   (both zero-padded)
    {
        float v0 = tl[0][tid] * g[0][tid];
        float v1 = tl[1][tid] * g[1][tid];
#pragma unroll
        for (int off = 32; off > 0; off >>= 1) {
            v0 += __shfl_xor(v0, off, 64);
            v1 += __shfl_xor(v1, off, 64);
        }
        if (lane == 0) { red[wid][0] = v0; red[wid][1] = v1; }
        __syncthreads();
        if (tid == 0) {
            avgv[0] = red[0][0] + red[1][0] + red[2][0] + red[3][0];
            avgv[1] = red[0][1] + red[1][1] + red[2][1] + red[3][1];
        }
    }
    __syncthreads();

    // ---- Phase D: fit[r][m] = sum_n tl[r][n] * X[n][m]   (wave-chunked n, x4)
    {
        float4 f00 = {0,0,0,0}, f01 = {0,0,0,0};
        float4 f10 = {0,0,0,0}, f11 = {0,0,0,0};
        for (int jj = 0; jj < cnt; jj += 4) {
            const int n0 = nb + jj;
            const float4 xa0 = Xb4[(size_t)(n0  )*128 + lane];
            const float4 xb0 = Xb4[(size_t)(n0  )*128 + 64 + lane];
            const float4 xa1 = Xb4[(size_t)(n0+1)*128 + lane];
            const float4 xb1 = Xb4[(size_t)(n0+1)*128 + 64 + lane];
            const float4 xa2 = Xb4[(size_t)(n0+2)*128 + lane];
            const float4 xb2 = Xb4[(size_t)(n0+2)*128 + 64 + lane];
            const float4 xa3 = Xb4[(size_t)(n0+3)*128 + lane];
            const float4 xb3 = Xb4[(size_t)(n0+3)*128 + 64 + lane];
            const float ta0 = tl[0][n0],   tb0 = tl[1][n0];
            const float ta1 = tl[0][n0+1], tb1 = tl[1][n0+1];
            const float ta2 = tl[0][n0+2], tb2 = tl[1][n0+2];
            const float ta3 = tl[0][n0+3], tb3 = tl[1][n0+3];
            fma4(f00, ta0, xa0); fma4(f00, ta1, xa1); fma4(f00, ta2, xa2); fma4(f00, ta3, xa3);
            fma4(f01, ta0, xb0); fma4(f01, ta1, xb1); fma4(f01, ta2, xb2); fma4(f01, ta3, xb3);
            fma4(f10, tb0, xa0); fma4(f10, tb1, xa1); fma4(f10, tb2, xa2); fma4(f10, tb3, xa3);
            fma4(f11, tb0, xb0); fma4(f11, tb1, xb1); fma4(f11, tb2, xb2); fma4(f11, tb3, xb3);
        }
        sp[wid][0][lane]      = f00;
        sp[wid][0][64 + lane] = f01;
        sp[wid][1][lane]      = f10;
        sp[wid][1][64 + lane] = f11;
    }
    __syncthreads();
    {
        const float a0 = avgv[0], a1 = avgv[1];
        float* const o0 = out + ((size_t)b * N_ + i0) * E_;
        float* const o1 = o0 + E_;
#pragma unroll
        for (int h = 0; h < 2; ++h) {
            const int m = tid + h * 256;
            const float fit0 = spf[0*512+m] + spf[2*512+m] + spf[4*512+m] + spf[6*512+m];
            const float fit1 = spf[1*512+m] + spf[3*512+m] + spf[5*512+m] + spf[7*512+m];
            o0[m] = xi[0][m] * (1.f + fit0 - a0);
            o1[m] = xi[1][m] * (1.f + fit1 - a1);
        }
    }
}

// ---------------------------------------------------------------------------
extern "C" void kernel_launch(void* const* d_in, const int* in_sizes, int n_in,
                              void* d_out, int out_size, void* d_ws, size_t ws_size,
                              hipStream_t stream) {
    const float* X  = (const float*)d_in[0];   // (B,N,E)
    const float* Qw = (const float*)d_in[1];   // (N,N)
    const float* Kw = (const float*)d_in[2];   // (N,N)
    float* out = (float*)d_out;                // (B,N,E)

    float* QwT   = (float*)d_ws;               // 256 KB
    float* Gpart = QwT + (size_t)N_ * N_;      // 16 * 256 KB = 4 MB

    prep_kernel<<<dim3(4, 4, 17), dim3(16, 16), 0, stream>>>(X, Qw, QwT, Gpart);
    fused_kernel<<<B_ * (N_ / 2), 256, 0, stream>>>(X, Kw, QwT, Gpart, out);
}

// Round 6
// 82.079 us; speedup vs baseline: 1.5232x; 1.0083x over previous
//
#include <hip/hip_runtime.h>

// Problem constants: B=4, N=256, E=512, fp32.
#define B_ 4
#define N_ 256
#define E_ 512

// ws layout (floats): QwT[256*256], Gpart[16][256*256]  (~4.25 MB total)

// ---------------------------------------------------------------------------
// prep_kernel: grid (4,4,17), block (16,16).  [unchanged from round 5]
//  bz 0..15: split-K Gram partial; bz==16: Qw transpose.
// ---------------------------------------------------------------------------
__global__ __launch_bounds__(256) void prep_kernel(
    const float* __restrict__ X, const float* __restrict__ Qw,
    float* __restrict__ QwT, float* __restrict__ Gpart) {

    const int bx = blockIdx.x, by = blockIdx.y, bz = blockIdx.z;
    const int tx = threadIdx.x, ty = threadIdx.y;
    const int tid = ty * 16 + tx;

    if (bz == 16) {
        __shared__ float tt[64][68];
        const int r = tid >> 2, c0 = tid & 3;
#pragma unroll
        for (int cc = 0; cc < 4; ++cc) {
            const int c = (c0 + cc * 4) * 4;
            const float4 v = *(const float4*)&Qw[(by * 64 + r) * N_ + bx * 64 + c];
            tt[c + 0][r] = v.x; tt[c + 1][r] = v.y;
            tt[c + 2][r] = v.z; tt[c + 3][r] = v.w;
        }
        __syncthreads();
#pragma unroll
        for (int cc = 0; cc < 4; ++cc) {
            const int c = (c0 + cc * 4) * 4;
            const float4 v = *(const float4*)&tt[r][c];
            *(float4*)&QwT[(bx * 64 + r) * N_ + by * 64 + c] = v;
        }
        return;
    }

    const int b = bz >> 2, kq = bz & 3;
    const float* __restrict__ Xb = X + (size_t)b * N_ * E_;
    __shared__ float At[32][68];
    __shared__ float Bt[32][68];
    float acc[4][4] = {};
    const int r = tid >> 2, c0 = tid & 3;

    for (int k0 = kq * 128; k0 < kq * 128 + 128; k0 += 32) {
        {
            const float4 va = *(const float4*)&Xb[(size_t)(by * 64 + r) * E_ + k0 + c0 * 8];
            const float4 vb = *(const float4*)&Xb[(size_t)(by * 64 + r) * E_ + k0 + c0 * 8 + 4];
            At[c0*8+0][r] = va.x; At[c0*8+1][r] = va.y; At[c0*8+2][r] = va.z; At[c0*8+3][r] = va.w;
            At[c0*8+4][r] = vb.x; At[c0*8+5][r] = vb.y; At[c0*8+6][r] = vb.z; At[c0*8+7][r] = vb.w;
            const float4 wa = *(const float4*)&Xb[(size_t)(bx * 64 + r) * E_ + k0 + c0 * 8];
            const float4 wb = *(const float4*)&Xb[(size_t)(bx * 64 + r) * E_ + k0 + c0 * 8 + 4];
            Bt[c0*8+0][r] = wa.x; Bt[c0*8+1][r] = wa.y; Bt[c0*8+2][r] = wa.z; Bt[c0*8+3][r] = wa.w;
            Bt[c0*8+4][r] = wb.x; Bt[c0*8+5][r] = wb.y; Bt[c0*8+6][r] = wb.z; Bt[c0*8+7][r] = wb.w;
        }
        __syncthreads();
#pragma unroll
        for (int kk = 0; kk < 32; ++kk) {
            const float4 a  = *(const float4*)&At[kk][ty * 4];
            const float4 bb = *(const float4*)&Bt[kk][tx * 4];
            acc[0][0] += a.x*bb.x; acc[0][1] += a.x*bb.y; acc[0][2] += a.x*bb.z; acc[0][3] += a.x*bb.w;
            acc[1][0] += a.y*bb.x; acc[1][1] += a.y*bb.y; acc[1][2] += a.y*bb.z; acc[1][3] += a.y*bb.w;
            acc[2][0] += a.z*bb.x; acc[2][1] += a.z*bb.y; acc[2][2] += a.z*bb.z; acc[2][3] += a.z*bb.w;
            acc[3][0] += a.w*bb.x; acc[3][1] += a.w*bb.y; acc[3][2] += a.w*bb.z; acc[3][3] += a.w*bb.w;
        }
        __syncthreads();
    }
    float* gout = Gpart + ((size_t)(kq * 4 + b) * N_ + by * 64 + ty * 4) * N_ + bx * 64 + tx * 4;
#pragma unroll
    for (int qi = 0; qi < 4; ++qi)
        *(float4*)&gout[(size_t)qi * N_] =
            make_float4(acc[qi][0], acc[qi][1], acc[qi][2], acc[qi][3]);
}

__device__ __forceinline__ void fma4(float4& a, float c, const float4& v) {
    a.x += c * v.x; a.y += c * v.y; a.z += c * v.z; a.w += c * v.w;
}

// ---------------------------------------------------------------------------
// fused: per-row-pair s -> t -> avg -> fit -> out.
//  - transposed coefficient arrays gT/sT/tT[N][4] (float2 broadcast reads)
//  - unroll-8 load pipelines in B/C/D (8-16 L2 loads in flight per wave)
//  - complementary dispatch remap: co-resident blocks (c, c+256) get spans
//    2j and 254-2j -> uniform per-CU work.
// grid 512, block 256 (4 waves).
// ---------------------------------------------------------------------------
__global__ __launch_bounds__(256) void fused_kernel(
    const float* __restrict__ X, const float* __restrict__ Kw,
    const float* __restrict__ QwT, const float* __restrict__ Gpart,
    float* __restrict__ out) {

    const int blk = blockIdx.x;
    const int b   = blk >> 7;
    const int j   = blk & 127;
    const int jr  = (b >= 2) ? (127 - j) : j;
    const int i0  = jr * 2;
    const int imax = i0 + 1;

    const int tid  = threadIdx.x;
    const int lane = tid & 63, wid = tid >> 6;

    const float4* __restrict__ Xb4 = (const float4*)(X + (size_t)b * N_ * E_);
    const float4* __restrict__ Kw4 = (const float4*)Kw;     // row stride 64
    const float4* __restrict__ Qt4 = (const float4*)QwT;    // row stride 64

    __shared__ float  xi[2][E_];       // 4 KB
    __shared__ float  gT[N_][4];       // [n][r], r=0,1 used; zero-padded
    __shared__ float  sT[N_][4];
    __shared__ float  tT[N_][4];
    __shared__ float4 sp[4][2][128];   // 16 KB partial-reduce buffer
    __shared__ float  avgv[2];
    __shared__ float  red[4][2];
    float* const spf = (float*)sp;     // spf[(w*2+r)*512 + idx]

    // ---- load x rows; gT from Gpart (sum 4 K-quarters), masked + padded
    {
        const int r = tid >> 7, c = tid & 127;
        ((float4*)xi[r])[c] = Xb4[(size_t)(i0 + r) * 128 + c];
    }
    {
        float s0 = 0.f, s1 = 0.f;
#pragma unroll
        for (int q = 0; q < 4; ++q) {
            s0 += Gpart[((size_t)(q * 4 + b) * N_ + i0)     * N_ + tid];
            s1 += Gpart[((size_t)(q * 4 + b) * N_ + i0 + 1) * N_ + tid];
        }
        gT[tid][0] = (tid <= i0)   ? s0 : 0.f;
        gT[tid][1] = (tid <= imax) ? s1 : 0.f;
        gT[tid][2] = 0.f; gT[tid][3] = 0.f;
    }
    __syncthreads();

    // reduction bound: multiple of 32 (unroll 8), >= imax+1, <= 256
    const int Mc  = (imax + 32) & ~31;
    const int cnt = Mc >> 2;           // per-wave chunk, multiple of 8
    const int nb  = wid * cnt;

    // ---- Phase B: s[r][p] = sum_n gT[n][r] * Kw[n][p]   (wave-chunked n)
    {
        float4 a0 = {0,0,0,0}, a1 = {0,0,0,0};
        for (int t8 = 0; t8 < cnt; t8 += 8) {
            const int n0 = nb + t8;
#pragma unroll
            for (int u = 0; u < 8; ++u) {
                const float4 kv = Kw4[(size_t)(n0 + u) * 64 + lane];
                const float2 gp = *(const float2*)&gT[n0 + u][0];
                fma4(a0, gp.x, kv);
                fma4(a1, gp.y, kv);
            }
        }
        sp[wid][0][lane] = a0;
        sp[wid][1][lane] = a1;
    }
    __syncthreads();
    {
        const float s0 = spf[0*512+tid] + spf[2*512+tid] + spf[4*512+tid] + spf[6*512+tid];
        const float s1 = spf[1*512+tid] + spf[3*512+tid] + spf[5*512+tid] + spf[7*512+tid];
        sT[tid][0] = (tid <= i0)   ? s0 : 0.f;
        sT[tid][1] = (tid <= imax) ? s1 : 0.f;
    }
    __syncthreads();

    // ---- Phase C: t[r][n] = sum_p sT[p][r] * QwT[p][n]   (wave-chunked p)
    {
        float4 a0 = {0,0,0,0}, a1 = {0,0,0,0};
        for (int t8 = 0; t8 < cnt; t8 += 8) {
            const int p0 = nb + t8;
#pragma unroll
            for (int u = 0; u < 8; ++u) {
                const float4 qv = Qt4[(size_t)(p0 + u) * 64 + lane];
                const float2 spr = *(const float2*)&sT[p0 + u][0];
                fma4(a0, spr.x, qv);
                fma4(a1, spr.y, qv);
            }
        }
        sp[wid][0][lane] = a0;
        sp[wid][1][lane] = a1;
    }
    __syncthreads();
    {
        const float t0 = spf[0*512+tid] + spf[2*512+tid] + spf[4*512+tid] + spf[6*512+tid];
        const float t1 = spf[1*512+tid] + spf[3*512+tid] + spf[5*512+tid] + spf[7*512+tid];
        tT[tid][0] = (tid <= i0)   ? t0 : 0.f;
        tT[tid][1] = (tid <= imax) ? t1 : 0.f;
    }
    __syncthreads();

    // ---- avg[r] = sum_n tT[n][r] * gT[n][r]   (both zero-padded)
    {
        float v0 = tT[tid][0] * gT[tid][0];
        float v1 = tT[tid][1] * gT[tid][1];
#pragma unroll
        for (int off = 32; off > 0; off >>= 1) {
            v0 += __shfl_xor(v0, off, 64);
            v1 += __shfl_xor(v1, off, 64);
        }
        if (lane == 0) { red[wid][0] = v0; red[wid][1] = v1; }
        __syncthreads();
        if (tid == 0) {
            avgv[0] = red[0][0] + red[1][0] + red[2][0] + red[3][0];
            avgv[1] = red[0][1] + red[1][1] + red[2][1] + red[3][1];
        }
    }
    __syncthreads();

    // ---- Phase D: fit[r][m] = sum_n tT[n][r] * X[n][m]   (wave-chunked n)
    {
        float4 f00 = {0,0,0,0}, f01 = {0,0,0,0};
        float4 f10 = {0,0,0,0}, f11 = {0,0,0,0};
        for (int t8 = 0; t8 < cnt; t8 += 8) {
            const int n0 = nb + t8;
#pragma unroll
            for (int u = 0; u < 8; ++u) {
                const float4 xa = Xb4[(size_t)(n0 + u) * 128 + lane];
                const float4 xb = Xb4[(size_t)(n0 + u) * 128 + 64 + lane];
                const float2 tp = *(const float2*)&tT[n0 + u][0];
                fma4(f00, tp.x, xa); fma4(f01, tp.x, xb);
                fma4(f10, tp.y, xa); fma4(f11, tp.y, xb);
            }
        }
        sp[wid][0][lane]      = f00;
        sp[wid][0][64 + lane] = f01;
        sp[wid][1][lane]      = f10;
        sp[wid][1][64 + lane] = f11;
    }
    __syncthreads();
    {
        const float a0 = avgv[0], a1 = avgv[1];
        float* const o0 = out + ((size_t)b * N_ + i0) * E_;
        float* const o1 = o0 + E_;
#pragma unroll
        for (int h = 0; h < 2; ++h) {
            const int m = tid + h * 256;
            const float fit0 = spf[0*512+m] + spf[2*512+m] + spf[4*512+m] + spf[6*512+m];
            const float fit1 = spf[1*512+m] + spf[3*512+m] + spf[5*512+m] + spf[7*512+m];
            o0[m] = xi[0][m] * (1.f + fit0 - a0);
            o1[m] = xi[1][m] * (1.f + fit1 - a1);
        }
    }
}

// ---------------------------------------------------------------------------
extern "C" void kernel_launch(void* const* d_in, const int* in_sizes, int n_in,
                              void* d_out, int out_size, void* d_ws, size_t ws_size,
                              hipStream_t stream) {
    const float* X  = (const float*)d_in[0];   // (B,N,E)
    const float* Qw = (const float*)d_in[1];   // (N,N)
    const float* Kw = (const float*)d_in[2];   // (N,N)
    float* out = (float*)d_out;                // (B,N,E)

    float* QwT   = (float*)d_ws;               // 256 KB
    float* Gpart = QwT + (size_t)N_ * N_;      // 16 * 256 KB = 4 MB

    prep_kernel<<<dim3(4, 4, 17), dim3(16, 16), 0, stream>>>(X, Qw, QwT, Gpart);
    fused_kernel<<<B_ * (N_ / 2), 256, 0, stream>>>(X, Kw, QwT, Gpart, out);
}